// Round 5
// baseline (234.706 us; speedup 1.0000x reference)
//
#include <hip/hip_runtime.h>

#define NB 8
#define CC 256
#define HH 8
#define DD 32
#define LL 4096

typedef short v8s __attribute__((ext_vector_type(8)));
typedef float v4f __attribute__((ext_vector_type(4)));
typedef unsigned short v8u __attribute__((ext_vector_type(8)));
typedef unsigned short v4us __attribute__((ext_vector_type(4)));

__device__ __forceinline__ float4 ld4(const float* p) { return *(const float4*)p; }

// round-to-nearest-even fp32 -> bf16 (as ushort)
__device__ __forceinline__ unsigned short f2bf(float f) {
    union { float f; unsigned int u; } v; v.f = f;
    unsigned int r = (v.u + 0x7FFFu + ((v.u >> 16) & 1u)) >> 16;
    return (unsigned short)r;
}
__device__ __forceinline__ float bf2f(unsigned short u) {
    union { unsigned int u; float f; } v; v.u = ((unsigned int)u) << 16;
    return v.f;
}

// ---------------------------------------------------------------------------
// Convert both weight matrices fp32 -> bf16 in one launch.
// ---------------------------------------------------------------------------
__global__ __launch_bounds__(256) void cvt2_k(
    const float* __restrict__ a, const float* __restrict__ b,
    unsigned short* __restrict__ da, unsigned short* __restrict__ db,
    int na, int nb)
{
    int i = blockIdx.x * 256 + threadIdx.x;
    if (i < na) da[i] = f2bf(a[i]);
    else if (i - na < nb) db[i - na] = f2bf(b[i - na]);
}

// ---------------------------------------------------------------------------
// Transpose x[N,C,L] fp32 -> xb[N,L,C] bf16.
// ---------------------------------------------------------------------------
#define PADC 264
__global__ __launch_bounds__(256) void transpose_x_k(
    const float* __restrict__ x, unsigned short* __restrict__ xb)
{
    __shared__ unsigned short t[32][PADC];
    const int n = blockIdx.y;
    const int l0 = blockIdx.x * 32;
    const float* xn = x + (size_t)n * CC * LL;
    const int lam = threadIdx.x & 31;
    const int cb = threadIdx.x >> 5;
#pragma unroll
    for (int i = 0; i < 32; ++i) {
        int c = cb * 32 + i;
        t[lam][c] = f2bf(xn[(size_t)c * LL + l0 + lam]);
    }
    __syncthreads();
    unsigned short* dst = xb + ((size_t)n * LL + l0) * CC;
    const int tid = threadIdx.x;
#pragma unroll
    for (int i = 0; i < 4; ++i) {
        int f = i * 2048 + tid * 8;
        int lr = f >> 8;
        int c2 = f & 255;
        v8u val = *(const v8u*)&t[lr][c2];
        *(v8u*)(dst + f) = val;
    }
}

// ---------------------------------------------------------------------------
// Kernel 1: MFMA qkv GEMM, X-resident-in-registers variant.
// One block = (n, 128 l-rows); 4 waves x 32 l each. Each wave preloads its
// full K=256 X-slab (16 v8s) ONCE, then loops 6 j-tiles x 8 c-chunks,
// streaming weight fragments (L2-hot) -> 768 MFMAs per wave.
// Fused L2-norm for q (jt 0-1) and k (jt 2-3); bf16 packed stores.
// ---------------------------------------------------------------------------
__global__ __launch_bounds__(256, 1) void gemm_qkv_mfma(
    const unsigned short* __restrict__ xb, const unsigned short* __restrict__ wqb,
    const float* __restrict__ bqkv,
    unsigned short* __restrict__ q, unsigned short* __restrict__ k,
    unsigned short* __restrict__ v)
{
    const int n  = blockIdx.y;
    const int l0 = blockIdx.x * 128;
    const int tid = threadIdx.x;
    const int lane = tid & 63, w = tid >> 6;
    const int r = lane & 15, quad = lane >> 4;

    // Preload X: rows l = l0 + w*32 + nj*16 + r, chunks c*32 + quad*8
    v8s xv[2][8];
#pragma unroll
    for (int nj = 0; nj < 2; ++nj) {
        const unsigned short* xrow = xb + (size_t)n * LL * CC
                                   + (size_t)(l0 + w * 32 + nj * 16 + r) * CC + quad * 8;
#pragma unroll
        for (int c = 0; c < 8; ++c)
            xv[nj][c] = *(const v8s*)(xrow + c * 32);
    }

    const unsigned short* wbase = wqb + (size_t)r * CC + quad * 8;

#pragma unroll
    for (int jt = 0; jt < 6; ++jt) {
        v4f acc[8][2];
#pragma unroll
        for (int mi = 0; mi < 8; ++mi)
#pragma unroll
            for (int nj = 0; nj < 2; ++nj) acc[mi][nj] = (v4f)(0.f);

#pragma unroll
        for (int c = 0; c < 8; ++c) {
            v8s wv[8];
#pragma unroll
            for (int mi = 0; mi < 8; ++mi)
                wv[mi] = *(const v8s*)(wbase + (size_t)(jt * 128 + mi * 16) * CC + c * 32);
#pragma unroll
            for (int mi = 0; mi < 8; ++mi)
#pragma unroll
                for (int nj = 0; nj < 2; ++nj)
                    acc[mi][nj] = __builtin_amdgcn_mfma_f32_16x16x32_bf16(
                        wv[mi], xv[nj][c], acc[mi][nj], 0, 0, 0);
        }

        // ---- epilogue for this j-tile ----
        float bias[8][4];
#pragma unroll
        for (int mi = 0; mi < 8; ++mi)
            *(float4*)bias[mi] = *(const float4*)(bqkv + jt * 128 + mi * 16 + quad * 4);

        const int s = jt >> 1;                 // 0=q 1=k 2=v
        unsigned short* base = (s == 0 ? q : (s == 1 ? k : v));
        unsigned short* dstp[8];
#pragma unroll
        for (int mi = 0; mi < 8; ++mi) {
            int hh = (jt & 1) * 4 + (mi >> 1);
            int d0 = (mi & 1) * 16 + quad * 4;
            dstp[mi] = base + (size_t)(n * HH + hh) * LL * DD + d0;
        }

        if (s < 2) {
#pragma unroll
            for (int nj = 0; nj < 2; ++nj) {
                float t[8][4];
                float ss[4] = {0.f, 0.f, 0.f, 0.f};
#pragma unroll
                for (int mi = 0; mi < 8; ++mi)
#pragma unroll
                    for (int reg = 0; reg < 4; ++reg) {
                        float val = acc[mi][nj][reg] + bias[mi][reg];
                        t[mi][reg] = val;
                        ss[mi >> 1] += val * val;
                    }
#pragma unroll
                for (int h4 = 0; h4 < 4; ++h4) {
                    ss[h4] += __shfl_xor(ss[h4], 16);
                    ss[h4] += __shfl_xor(ss[h4], 32);
                    ss[h4] = rsqrtf(ss[h4]);
                }
                size_t l = (size_t)(l0 + w * 32 + nj * 16 + r);
#pragma unroll
                for (int mi = 0; mi < 8; ++mi) {
                    float rn = ss[mi >> 1];
                    v4us pk;
#pragma unroll
                    for (int reg = 0; reg < 4; ++reg) pk[reg] = f2bf(t[mi][reg] * rn);
                    *(v4us*)(dstp[mi] + l * DD) = pk;
                }
            }
        } else {
#pragma unroll
            for (int nj = 0; nj < 2; ++nj) {
                size_t l = (size_t)(l0 + w * 32 + nj * 16 + r);
#pragma unroll
                for (int mi = 0; mi < 8; ++mi) {
                    v4us pk;
#pragma unroll
                    for (int reg = 0; reg < 4; ++reg)
                        pk[reg] = f2bf(acc[mi][nj][reg] + bias[mi][reg]);
                    *(v4us*)(dstp[mi] + l * DD) = pk;
                }
            }
        }
    }
}

// ---------------------------------------------------------------------------
// Kernel 3: attn[n,h,d,e] = sum_l k[n,h,l,d] * v[n,h,l,e]   (bf16 in, fp32 acc)
// ---------------------------------------------------------------------------
__global__ __launch_bounds__(256) void attn_k(
    const unsigned short* __restrict__ k, const unsigned short* __restrict__ v,
    float* __restrict__ attn)
{
    __shared__ float red[4][1024];
    const int nh = blockIdx.y;
    const int wv = threadIdx.x >> 6;
    const int lane = threadIdx.x & 63;
    const int eg = lane & 7;
    const int dg = lane >> 3;
    const int l0 = blockIdx.x * 512 + wv * 128;
    const unsigned short* kb = k + (size_t)nh * LL * DD;
    const unsigned short* vb = v + (size_t)nh * LL * DD;
    float acc[4][4] = {};
#pragma unroll 4
    for (int l = l0; l < l0 + 128; ++l) {
        v4us k4 = *(const v4us*)(kb + (size_t)l * DD + dg * 4);
        v4us v4 = *(const v4us*)(vb + (size_t)l * DD + eg * 4);
        float ka[4] = {bf2f(k4[0]), bf2f(k4[1]), bf2f(k4[2]), bf2f(k4[3])};
        float va[4] = {bf2f(v4[0]), bf2f(v4[1]), bf2f(v4[2]), bf2f(v4[3])};
#pragma unroll
        for (int dp = 0; dp < 4; ++dp)
#pragma unroll
            for (int ep = 0; ep < 4; ++ep)
                acc[dp][ep] += ka[dp] * va[ep];
    }
#pragma unroll
    for (int dp = 0; dp < 4; ++dp)
#pragma unroll
        for (int ep = 0; ep < 4; ++ep)
            red[wv][(dg * 4 + dp) * 32 + eg * 4 + ep] = acc[dp][ep];
    __syncthreads();
    float* ap = attn + (size_t)nh * 1024;
    for (int i = threadIdx.x; i < 1024; i += 256)
        atomicAdd(&ap[i], red[0][i] + red[1][i] + red[2][i] + red[3][i]);
}

// ---------------------------------------------------------------------------
// Kernel 4: one block = 256 tokens of one (n,h); bf16 q/v in, bf16 mid out.
// ---------------------------------------------------------------------------
#define TOK 256
__global__ __launch_bounds__(256) void mid_k(
    const unsigned short* __restrict__ q, const unsigned short* __restrict__ v,
    const float* __restrict__ attn, const float* __restrict__ wd,
    unsigned short* __restrict__ midb)
{
    __shared__ float vt[TOK + 8][32];
    const int nh = blockIdx.y;
    const int n = nh >> 3, hh = nh & 7;
    const int l0 = blockIdx.x * TOK;
    const int tid = threadIdx.x;
    const int row = tid >> 5;
    const int e = tid & 31;
    const unsigned short* vb = v + (size_t)nh * LL * DD;

    for (int f = tid; f < (TOK + 8) * 32; f += 256) {
        int rr = f >> 5, ee = f & 31;
        int l = l0 - 4 + rr;
        vt[rr][ee] = (l >= 0 && l < LL) ? bf2f(vb[(size_t)l * DD + ee]) : 0.f;
    }

    float atc[32];
    const float* ap = attn + (size_t)nh * 1024 + e;
#pragma unroll
    for (int d = 0; d < 32; ++d) atc[d] = ap[d * 32];

    float wc[9];
#pragma unroll
    for (int r9 = 0; r9 < 9; ++r9) wc[r9] = wd[hh * 9 + r9];

    __syncthreads();

    const unsigned short* qb = q + (size_t)nh * LL * DD;
    unsigned short* ob = midb + ((size_t)n * LL) * CC + hh * DD + e;

    for (int it = 0; it < TOK / 8; ++it) {
        int lr = it * 8 + row;
        int l = l0 + lr;
        const unsigned short* qrow = qb + (size_t)l * DD;
        float s = 0.f;
#pragma unroll
        for (int d8 = 0; d8 < 4; ++d8) {
            v8u q8 = *(const v8u*)(qrow + d8 * 8);
#pragma unroll
            for (int jj = 0; jj < 8; ++jj)
                s += bf2f(q8[jj]) * atc[d8 * 8 + jj];
        }
        float t = 0.5f * vt[lr + 4][e] + 0.31830988618379067f * s;
        float ss = t * t;
#pragma unroll
        for (int off = 16; off; off >>= 1) ss += __shfl_xor(ss, off, 32);
        float o = t * rsqrtf(ss);
        float dv = 0.f;
#pragma unroll
        for (int r9 = 0; r9 < 9; ++r9) dv += wc[r9] * vt[lr + r9][e];
        ob[(size_t)l * CC] = f2bf(o + dv);
    }
}

// ---------------------------------------------------------------------------
// Kernel 5: MFMA proj GEMM (M=j, N=l), coalesced stores along l.
// ---------------------------------------------------------------------------
__global__ __launch_bounds__(256) void gemm_proj_mfma(
    const unsigned short* __restrict__ midb, const unsigned short* __restrict__ wpb,
    const float* __restrict__ bp, float* __restrict__ out)
{
    const int n  = blockIdx.z;
    const int j0 = blockIdx.x * 128;
    const int l0 = blockIdx.y * 128;
    const int tid = threadIdx.x;
    const int lane = tid & 63, wave = tid >> 6;
    const int wr = wave >> 1, wc = wave & 1;
    const int r = lane & 15, quad = lane >> 4;

    const unsigned short* abase = wpb + (size_t)(j0 + wr * 64 + r) * CC + quad * 8;
    const unsigned short* bbase = midb + (size_t)n * LL * CC
                                + (size_t)(l0 + wc * 64 + r) * CC + quad * 8;

    v4f acc[4][4];
#pragma unroll
    for (int mi = 0; mi < 4; ++mi)
#pragma unroll
        for (int nj = 0; nj < 4; ++nj) acc[mi][nj] = (v4f)(0.f);

    for (int c0 = 0; c0 < CC; c0 += 32) {
        v8s a[4], b[4];
#pragma unroll
        for (int mi = 0; mi < 4; ++mi) a[mi] = *(const v8s*)(abase + (size_t)mi * 16 * CC + c0);
#pragma unroll
        for (int nj = 0; nj < 4; ++nj) b[nj] = *(const v8s*)(bbase + (size_t)nj * 16 * CC + c0);
#pragma unroll
        for (int mi = 0; mi < 4; ++mi)
#pragma unroll
            for (int nj = 0; nj < 4; ++nj)
                acc[mi][nj] = __builtin_amdgcn_mfma_f32_16x16x32_bf16(a[mi], b[nj], acc[mi][nj], 0, 0, 0);
    }

#pragma unroll
    for (int mi = 0; mi < 4; ++mi)
#pragma unroll
        for (int reg = 0; reg < 4; ++reg) {
            int j = j0 + wr * 64 + mi * 16 + quad * 4 + reg;
            float bias = bp[j];
#pragma unroll
            for (int nj = 0; nj < 4; ++nj) {
                int l = l0 + wc * 64 + nj * 16 + r;
                out[((size_t)n * CC + j) * LL + l] = acc[mi][nj][reg] + bias;
            }
        }
}

// ---------------------------------------------------------------------------
extern "C" void kernel_launch(void* const* d_in, const int* in_sizes, int n_in,
                              void* d_out, int out_size, void* d_ws, size_t ws_size,
                              hipStream_t stream)
{
    const float* x     = (const float*)d_in[0];
    const float* wqkv  = (const float*)d_in[1];
    const float* bqkv  = (const float*)d_in[2];
    const float* wproj = (const float*)d_in[3];
    const float* bproj = (const float*)d_in[4];
    const float* wd    = (const float*)d_in[5];
    float* out = (float*)d_out;

    const size_t QKV = (size_t)NB * HH * LL * DD;       // 8388608 elems
    unsigned short* q = (unsigned short*)d_ws;
    unsigned short* k = q + QKV;
    unsigned short* v = k + QKV;
    float* attn = (float*)(v + QKV);                    // 65536 floats
    unsigned short* xb = (unsigned short*)(attn + (size_t)NB * HH * DD * DD);
    unsigned short* midb = xb;                          // disjoint live ranges
    unsigned short* wqb = xb + (size_t)NB * LL * CC;
    unsigned short* wpb = wqb + 3 * CC * CC;

    hipMemsetAsync(attn, 0, (size_t)NB * HH * DD * DD * sizeof(float), stream);

    cvt2_k<<<1024, 256, 0, stream>>>(wqkv, wproj, wqb, wpb, 3 * CC * CC, CC * CC);
    transpose_x_k<<<dim3(128, 8), 256, 0, stream>>>(x, xb);
    gemm_qkv_mfma<<<dim3(32, 8), 256, 0, stream>>>(xb, wqb, bqkv, q, k, v);
    attn_k<<<dim3(8, 64), 256, 0, stream>>>(k, v, attn);
    mid_k<<<dim3(LL / TOK, 64), 256, 0, stream>>>(q, v, attn, wd, midb);
    gemm_proj_mfma<<<dim3(2, 32, 8), 256, 0, stream>>>(midb, wpb, bproj, out);
}

// Round 6
// 219.309 us; speedup vs baseline: 1.0702x; 1.0702x over previous
//
#include <hip/hip_runtime.h>

#define NB 8
#define CC 256
#define HH 8
#define DD 32
#define LL 4096

typedef short v8s __attribute__((ext_vector_type(8)));
typedef float v4f __attribute__((ext_vector_type(4)));
typedef unsigned short v8u __attribute__((ext_vector_type(8)));
typedef unsigned short v4us __attribute__((ext_vector_type(4)));

__device__ __forceinline__ float4 ld4(const float* p) { return *(const float4*)p; }

// round-to-nearest-even fp32 -> bf16 (as ushort)
__device__ __forceinline__ unsigned short f2bf(float f) {
    union { float f; unsigned int u; } v; v.f = f;
    unsigned int r = (v.u + 0x7FFFu + ((v.u >> 16) & 1u)) >> 16;
    return (unsigned short)r;
}
__device__ __forceinline__ float bf2f(unsigned short u) {
    union { unsigned int u; float f; } v; v.u = ((unsigned int)u) << 16;
    return v.f;
}

// ---------------------------------------------------------------------------
// Convert both weight matrices fp32 -> bf16 in one launch.
// ---------------------------------------------------------------------------
__global__ __launch_bounds__(256) void cvt2_k(
    const float* __restrict__ a, const float* __restrict__ b,
    unsigned short* __restrict__ da, unsigned short* __restrict__ db,
    int na, int nb)
{
    int i = blockIdx.x * 256 + threadIdx.x;
    if (i < na) da[i] = f2bf(a[i]);
    else if (i - na < nb) db[i - na] = f2bf(b[i - na]);
}

// ---------------------------------------------------------------------------
// Transpose x[N,C,L] fp32 -> xb[N,L,C] bf16.
// ---------------------------------------------------------------------------
#define PADC 264
__global__ __launch_bounds__(256) void transpose_x_k(
    const float* __restrict__ x, unsigned short* __restrict__ xb)
{
    __shared__ unsigned short t[32][PADC];
    const int n = blockIdx.y;
    const int l0 = blockIdx.x * 32;
    const float* xn = x + (size_t)n * CC * LL;
    const int lam = threadIdx.x & 31;
    const int cb = threadIdx.x >> 5;
#pragma unroll
    for (int i = 0; i < 32; ++i) {
        int c = cb * 32 + i;
        t[lam][c] = f2bf(xn[(size_t)c * LL + l0 + lam]);
    }
    __syncthreads();
    unsigned short* dst = xb + ((size_t)n * LL + l0) * CC;
    const int tid = threadIdx.x;
#pragma unroll
    for (int i = 0; i < 4; ++i) {
        int f = i * 2048 + tid * 8;
        int lr = f >> 8;
        int c2 = f & 255;
        v8u val = *(const v8u*)&t[lr][c2];
        *(v8u*)(dst + f) = val;
    }
}

// ---------------------------------------------------------------------------
// Kernel 1: MFMA qkv GEMM.  M = j (256-wide tile -> one full tensor q/k/v),
// N = l (128), K = 256.  Grid 768 (3 j-tiles x 32 l-tiles x 8 n), 1D with
// XCD swizzle: the 3 j-blocks sharing an (l,n) X-tile land on the SAME XCD
// (bid%8 round-robin), so X re-reads are per-XCD L2 hits.
// Wave = 128j x 64l: acc[8][4], 32 MFMA : 12 loads per K-step.
// Fused per-head L2 norm for q/k; v4us bf16 packed stores.
// ---------------------------------------------------------------------------
__global__ __launch_bounds__(256, 2) void gemm_qkv_mfma(
    const unsigned short* __restrict__ xb, const unsigned short* __restrict__ wqb,
    const float* __restrict__ bqkv,
    unsigned short* __restrict__ q, unsigned short* __restrict__ k,
    unsigned short* __restrict__ v)
{
    const int bid  = blockIdx.x;
    const int xcd  = bid & 7;
    const int slot = bid >> 3;        // 0..95
    const int jt   = slot % 3;        // j-tile (same-XCD trio shares (l,n))
    const int p    = slot / 3;        // 0..31
    const int gp   = xcd * 32 + p;    // 0..255 (l,n) pair
    const int l0   = (gp & 31) * 128;
    const int n    = gp >> 5;
    const int j0   = jt * 256;

    const int tid = threadIdx.x;
    const int lane = tid & 63, wave = tid >> 6;
    const int wr = wave >> 1, wc = wave & 1;
    const int r = lane & 15, quad = lane >> 4;

    const unsigned short* abase = wqb + (size_t)(j0 + wr * 128 + r) * CC + quad * 8;
    const unsigned short* bbase = xb + (size_t)n * LL * CC
                                + (size_t)(l0 + wc * 64 + r) * CC + quad * 8;

    v4f acc[8][4];
#pragma unroll
    for (int mi = 0; mi < 8; ++mi)
#pragma unroll
        for (int nj = 0; nj < 4; ++nj) acc[mi][nj] = (v4f)(0.f);

#pragma unroll
    for (int c0 = 0; c0 < CC; c0 += 32) {
        v8s a[8], b[4];
#pragma unroll
        for (int mi = 0; mi < 8; ++mi) a[mi] = *(const v8s*)(abase + (size_t)mi * 16 * CC + c0);
#pragma unroll
        for (int nj = 0; nj < 4; ++nj) b[nj] = *(const v8s*)(bbase + (size_t)nj * 16 * CC + c0);
#pragma unroll
        for (int mi = 0; mi < 8; ++mi)
#pragma unroll
            for (int nj = 0; nj < 4; ++nj)
                acc[mi][nj] = __builtin_amdgcn_mfma_f32_16x16x32_bf16(a[mi], b[nj], acc[mi][nj], 0, 0, 0);
    }

    // ---- epilogue ----  row j = j0 + wr*128 + mi*16 + quad*4 + reg
    unsigned short* base = (jt == 0 ? q : (jt == 1 ? k : v));

    float bias[8][4];
#pragma unroll
    for (int mi = 0; mi < 8; ++mi)
        *(float4*)bias[mi] = *(const float4*)(bqkv + j0 + wr * 128 + mi * 16 + quad * 4);

    unsigned short* dstp[8];
#pragma unroll
    for (int mi = 0; mi < 8; ++mi) {
        int hh = wr * 4 + (mi >> 1);
        int d0 = (mi & 1) * 16 + quad * 4;
        dstp[mi] = base + (size_t)(n * HH + hh) * LL * DD + d0;
    }

    if (jt < 2) {
#pragma unroll
        for (int nj = 0; nj < 4; ++nj) {
            float t[8][4];
            float ss[4] = {0.f, 0.f, 0.f, 0.f};
#pragma unroll
            for (int mi = 0; mi < 8; ++mi)
#pragma unroll
                for (int reg = 0; reg < 4; ++reg) {
                    float val = acc[mi][nj][reg] + bias[mi][reg];
                    t[mi][reg] = val;
                    ss[mi >> 1] += val * val;
                }
#pragma unroll
            for (int h4 = 0; h4 < 4; ++h4) {
                ss[h4] += __shfl_xor(ss[h4], 16);
                ss[h4] += __shfl_xor(ss[h4], 32);
                ss[h4] = rsqrtf(ss[h4]);
            }
            size_t l = (size_t)(l0 + wc * 64 + nj * 16 + r);
#pragma unroll
            for (int mi = 0; mi < 8; ++mi) {
                float rn = ss[mi >> 1];
                v4us pk;
#pragma unroll
                for (int reg = 0; reg < 4; ++reg) pk[reg] = f2bf(t[mi][reg] * rn);
                *(v4us*)(dstp[mi] + l * DD) = pk;
            }
        }
    } else {
#pragma unroll
        for (int nj = 0; nj < 4; ++nj) {
            size_t l = (size_t)(l0 + wc * 64 + nj * 16 + r);
#pragma unroll
            for (int mi = 0; mi < 8; ++mi) {
                v4us pk;
#pragma unroll
                for (int reg = 0; reg < 4; ++reg)
                    pk[reg] = f2bf(acc[mi][nj][reg] + bias[mi][reg]);
                *(v4us*)(dstp[mi] + l * DD) = pk;
            }
        }
    }
}

// ---------------------------------------------------------------------------
// Kernel 3: attn[n,h,d,e] = sum_l k[n,h,l,d] * v[n,h,l,e]   (bf16 in, fp32 acc)
// ---------------------------------------------------------------------------
__global__ __launch_bounds__(256) void attn_k(
    const unsigned short* __restrict__ k, const unsigned short* __restrict__ v,
    float* __restrict__ attn)
{
    __shared__ float red[4][1024];
    const int nh = blockIdx.y;
    const int wv = threadIdx.x >> 6;
    const int lane = threadIdx.x & 63;
    const int eg = lane & 7;
    const int dg = lane >> 3;
    const int l0 = blockIdx.x * 512 + wv * 128;
    const unsigned short* kb = k + (size_t)nh * LL * DD;
    const unsigned short* vb = v + (size_t)nh * LL * DD;
    float acc[4][4] = {};
#pragma unroll 4
    for (int l = l0; l < l0 + 128; ++l) {
        v4us k4 = *(const v4us*)(kb + (size_t)l * DD + dg * 4);
        v4us v4 = *(const v4us*)(vb + (size_t)l * DD + eg * 4);
        float ka[4] = {bf2f(k4[0]), bf2f(k4[1]), bf2f(k4[2]), bf2f(k4[3])};
        float va[4] = {bf2f(v4[0]), bf2f(v4[1]), bf2f(v4[2]), bf2f(v4[3])};
#pragma unroll
        for (int dp = 0; dp < 4; ++dp)
#pragma unroll
            for (int ep = 0; ep < 4; ++ep)
                acc[dp][ep] += ka[dp] * va[ep];
    }
#pragma unroll
    for (int dp = 0; dp < 4; ++dp)
#pragma unroll
        for (int ep = 0; ep < 4; ++ep)
            red[wv][(dg * 4 + dp) * 32 + eg * 4 + ep] = acc[dp][ep];
    __syncthreads();
    float* ap = attn + (size_t)nh * 1024;
    for (int i = threadIdx.x; i < 1024; i += 256)
        atomicAdd(&ap[i], red[0][i] + red[1][i] + red[2][i] + red[3][i]);
}

// ---------------------------------------------------------------------------
// Kernel 4: one block = 256 tokens of one (n,h); bf16 q/v in, bf16 mid out.
// ---------------------------------------------------------------------------
#define TOK 256
__global__ __launch_bounds__(256) void mid_k(
    const unsigned short* __restrict__ q, const unsigned short* __restrict__ v,
    const float* __restrict__ attn, const float* __restrict__ wd,
    unsigned short* __restrict__ midb)
{
    __shared__ float vt[TOK + 8][32];
    const int nh = blockIdx.y;
    const int n = nh >> 3, hh = nh & 7;
    const int l0 = blockIdx.x * TOK;
    const int tid = threadIdx.x;
    const int row = tid >> 5;
    const int e = tid & 31;
    const unsigned short* vb = v + (size_t)nh * LL * DD;

    for (int f = tid; f < (TOK + 8) * 32; f += 256) {
        int rr = f >> 5, ee = f & 31;
        int l = l0 - 4 + rr;
        vt[rr][ee] = (l >= 0 && l < LL) ? bf2f(vb[(size_t)l * DD + ee]) : 0.f;
    }

    float atc[32];
    const float* ap = attn + (size_t)nh * 1024 + e;
#pragma unroll
    for (int d = 0; d < 32; ++d) atc[d] = ap[d * 32];

    float wc[9];
#pragma unroll
    for (int r9 = 0; r9 < 9; ++r9) wc[r9] = wd[hh * 9 + r9];

    __syncthreads();

    const unsigned short* qb = q + (size_t)nh * LL * DD;
    unsigned short* ob = midb + ((size_t)n * LL) * CC + hh * DD + e;

    for (int it = 0; it < TOK / 8; ++it) {
        int lr = it * 8 + row;
        int l = l0 + lr;
        const unsigned short* qrow = qb + (size_t)l * DD;
        float s = 0.f;
#pragma unroll
        for (int d8 = 0; d8 < 4; ++d8) {
            v8u q8 = *(const v8u*)(qrow + d8 * 8);
#pragma unroll
            for (int jj = 0; jj < 8; ++jj)
                s += bf2f(q8[jj]) * atc[d8 * 8 + jj];
        }
        float t = 0.5f * vt[lr + 4][e] + 0.31830988618379067f * s;
        float ss = t * t;
#pragma unroll
        for (int off = 16; off; off >>= 1) ss += __shfl_xor(ss, off, 32);
        float o = t * rsqrtf(ss);
        float dv = 0.f;
#pragma unroll
        for (int r9 = 0; r9 < 9; ++r9) dv += wc[r9] * vt[lr + r9][e];
        ob[(size_t)l * CC] = f2bf(o + dv);
    }
}

// ---------------------------------------------------------------------------
// Kernel 5: MFMA proj GEMM (M=j, N=l), coalesced stores along l.
// ---------------------------------------------------------------------------
__global__ __launch_bounds__(256) void gemm_proj_mfma(
    const unsigned short* __restrict__ midb, const unsigned short* __restrict__ wpb,
    const float* __restrict__ bp, float* __restrict__ out)
{
    const int n  = blockIdx.z;
    const int j0 = blockIdx.x * 128;
    const int l0 = blockIdx.y * 128;
    const int tid = threadIdx.x;
    const int lane = tid & 63, wave = tid >> 6;
    const int wr = wave >> 1, wc = wave & 1;
    const int r = lane & 15, quad = lane >> 4;

    const unsigned short* abase = wpb + (size_t)(j0 + wr * 64 + r) * CC + quad * 8;
    const unsigned short* bbase = midb + (size_t)n * LL * CC
                                + (size_t)(l0 + wc * 64 + r) * CC + quad * 8;

    v4f acc[4][4];
#pragma unroll
    for (int mi = 0; mi < 4; ++mi)
#pragma unroll
        for (int nj = 0; nj < 4; ++nj) acc[mi][nj] = (v4f)(0.f);

    for (int c0 = 0; c0 < CC; c0 += 32) {
        v8s a[4], b[4];
#pragma unroll
        for (int mi = 0; mi < 4; ++mi) a[mi] = *(const v8s*)(abase + (size_t)mi * 16 * CC + c0);
#pragma unroll
        for (int nj = 0; nj < 4; ++nj) b[nj] = *(const v8s*)(bbase + (size_t)nj * 16 * CC + c0);
#pragma unroll
        for (int mi = 0; mi < 4; ++mi)
#pragma unroll
            for (int nj = 0; nj < 4; ++nj)
                acc[mi][nj] = __builtin_amdgcn_mfma_f32_16x16x32_bf16(a[mi], b[nj], acc[mi][nj], 0, 0, 0);
    }

#pragma unroll
    for (int mi = 0; mi < 4; ++mi)
#pragma unroll
        for (int reg = 0; reg < 4; ++reg) {
            int j = j0 + wr * 64 + mi * 16 + quad * 4 + reg;
            float bias = bp[j];
#pragma unroll
            for (int nj = 0; nj < 4; ++nj) {
                int l = l0 + wc * 64 + nj * 16 + r;
                out[((size_t)n * CC + j) * LL + l] = acc[mi][nj][reg] + bias;
            }
        }
}

// ---------------------------------------------------------------------------
extern "C" void kernel_launch(void* const* d_in, const int* in_sizes, int n_in,
                              void* d_out, int out_size, void* d_ws, size_t ws_size,
                              hipStream_t stream)
{
    const float* x     = (const float*)d_in[0];
    const float* wqkv  = (const float*)d_in[1];
    const float* bqkv  = (const float*)d_in[2];
    const float* wproj = (const float*)d_in[3];
    const float* bproj = (const float*)d_in[4];
    const float* wd    = (const float*)d_in[5];
    float* out = (float*)d_out;

    const size_t QKV = (size_t)NB * HH * LL * DD;       // 8388608 elems
    unsigned short* q = (unsigned short*)d_ws;
    unsigned short* k = q + QKV;
    unsigned short* v = k + QKV;
    float* attn = (float*)(v + QKV);                    // 65536 floats
    unsigned short* xb = (unsigned short*)(attn + (size_t)NB * HH * DD * DD);
    unsigned short* midb = xb;                          // disjoint live ranges
    unsigned short* wqb = xb + (size_t)NB * LL * CC;
    unsigned short* wpb = wqb + 3 * CC * CC;

    hipMemsetAsync(attn, 0, (size_t)NB * HH * DD * DD * sizeof(float), stream);

    cvt2_k<<<1024, 256, 0, stream>>>(wqkv, wproj, wqb, wpb, 3 * CC * CC, CC * CC);
    transpose_x_k<<<dim3(128, 8), 256, 0, stream>>>(x, xb);
    gemm_qkv_mfma<<<768, 256, 0, stream>>>(xb, wqb, bqkv, q, k, v);
    attn_k<<<dim3(8, 64), 256, 0, stream>>>(k, v, attn);
    mid_k<<<dim3(LL / TOK, 64), 256, 0, stream>>>(q, v, attn, wd, midb);
    gemm_proj_mfma<<<dim3(2, 32, 8), 256, 0, stream>>>(midb, wpb, bproj, out);
}

// Round 7
// 203.554 us; speedup vs baseline: 1.1530x; 1.0774x over previous
//
#include <hip/hip_runtime.h>

#define NB 8
#define CC 256
#define HH 8
#define DD 32
#define LL 4096

typedef short v8s __attribute__((ext_vector_type(8)));
typedef float v4f __attribute__((ext_vector_type(4)));
typedef unsigned short v8u __attribute__((ext_vector_type(8)));
typedef unsigned short v4us __attribute__((ext_vector_type(4)));

__device__ __forceinline__ float4 ld4(const float* p) { return *(const float4*)p; }

// round-to-nearest-even fp32 -> bf16 (as ushort)
__device__ __forceinline__ unsigned short f2bf(float f) {
    union { float f; unsigned int u; } v; v.f = f;
    unsigned int r = (v.u + 0x7FFFu + ((v.u >> 16) & 1u)) >> 16;
    return (unsigned short)r;
}
__device__ __forceinline__ float bf2f(unsigned short u) {
    union { unsigned int u; float f; } v; v.u = ((unsigned int)u) << 16;
    return v.f;
}

// async global->LDS, 16 B per lane (dest = wave-uniform base + lane*16)
__device__ __forceinline__ void gl_lds16(const unsigned short* g, unsigned short* l) {
    __builtin_amdgcn_global_load_lds(
        (const __attribute__((address_space(1))) void*)g,
        (__attribute__((address_space(3))) void*)l, 16, 0, 0);
}

// ---------------------------------------------------------------------------
// Convert both weight matrices fp32 -> bf16 in one launch.
// ---------------------------------------------------------------------------
__global__ __launch_bounds__(256) void cvt2_k(
    const float* __restrict__ a, const float* __restrict__ b,
    unsigned short* __restrict__ da, unsigned short* __restrict__ db,
    int na, int nb)
{
    int i = blockIdx.x * 256 + threadIdx.x;
    if (i < na) da[i] = f2bf(a[i]);
    else if (i - na < nb) db[i - na] = f2bf(b[i - na]);
}

// ---------------------------------------------------------------------------
// Transpose x[N,C,L] fp32 -> xb[N,L,C] bf16.
// ---------------------------------------------------------------------------
#define PADC 264
__global__ __launch_bounds__(256) void transpose_x_k(
    const float* __restrict__ x, unsigned short* __restrict__ xb)
{
    __shared__ unsigned short t[32][PADC];
    const int n = blockIdx.y;
    const int l0 = blockIdx.x * 32;
    const float* xn = x + (size_t)n * CC * LL;
    const int lam = threadIdx.x & 31;
    const int cb = threadIdx.x >> 5;
#pragma unroll
    for (int i = 0; i < 32; ++i) {
        int c = cb * 32 + i;
        t[lam][c] = f2bf(xn[(size_t)c * LL + l0 + lam]);
    }
    __syncthreads();
    unsigned short* dst = xb + ((size_t)n * LL + l0) * CC;
    const int tid = threadIdx.x;
#pragma unroll
    for (int i = 0; i < 4; ++i) {
        int f = i * 2048 + tid * 8;
        int lr = f >> 8;
        int c2 = f & 255;
        v8u val = *(const v8u*)&t[lr][c2];
        *(v8u*)(dst + f) = val;
    }
}

// ---------------------------------------------------------------------------
// Kernel 1: MFMA qkv GEMM, m97-style LDS-staged pipeline.
// Tile 128j x 128l, BK=64 (4 K-iters).  Staging via global_load_lds w=16;
// XOR chunk swizzle (slot = chunk ^ (row&7)) applied on the GLOBAL source
// address so staging stays contiguous and ds_read_b128 is 2-way (free).
// Grid 1536, XCD swizzle: 6 j-tiles of an (l,n) X-tile share an XCD.
// Fused per-head L2 norm for q/k; v4us bf16 packed stores.
// ---------------------------------------------------------------------------
__global__ __launch_bounds__(256, 2) void gemm_qkv_mfma(
    const unsigned short* __restrict__ xb, const unsigned short* __restrict__ wqb,
    const float* __restrict__ bqkv,
    unsigned short* __restrict__ q, unsigned short* __restrict__ k,
    unsigned short* __restrict__ v)
{
    __shared__ __align__(16) unsigned short xs[8192];   // 128 rows x 64 k (swizzled)
    __shared__ __align__(16) unsigned short wsb[8192];

    const int bid  = blockIdx.x;
    const int xcd  = bid & 7;
    const int slot = bid >> 3;        // 0..191
    const int jt   = slot % 6;        // 6 j-tiles share (l,n) on one XCD
    const int p    = slot / 6;        // 0..31
    const int gp   = xcd * 32 + p;    // 0..255
    const int l0   = (gp & 31) * 128;
    const int n    = gp >> 5;
    const int j0   = jt * 128;

    const int tid = threadIdx.x;
    const int lane = tid & 63, wave = tid >> 6;
    const int wr = wave >> 1, wc = wave & 1;
    const int r = lane & 15, quad = lane >> 4;

    // staging: inst i covers rows i*32 + wave*8 + (lane>>3); chunk slot lane&7
    const int srow = wave * 8 + (lane >> 3);
    const int dchunk = (lane & 7) ^ (lane >> 3);     // global chunk for this slot
    const unsigned short* xg = xb + (size_t)n * LL * CC
                             + (size_t)(l0 + srow) * CC + dchunk * 8;
    const unsigned short* wg = wqb + (size_t)(j0 + srow) * CC + dchunk * 8;
    unsigned short* xls = xs + wave * 512 + lane * 8;
    unsigned short* wls = wsb + wave * 512 + lane * 8;

    v4f acc[4][4];
#pragma unroll
    for (int mi = 0; mi < 4; ++mi)
#pragma unroll
        for (int nj = 0; nj < 4; ++nj) acc[mi][nj] = (v4f)(0.f);

    const int jbase = wr * 64;  // j-quadrant of this wave
    const int lbase = wc * 64;

    for (int kt = 0; kt < 4; ++kt) {
        if (kt) __syncthreads();
        const int c0 = kt * 64;
#pragma unroll
        for (int i = 0; i < 4; ++i) {
            gl_lds16(xg + (size_t)i * 32 * CC + c0, xls + i * 2048);
            gl_lds16(wg + (size_t)i * 32 * CC + c0, wls + i * 2048);
        }
        __syncthreads();

        v8s a[4][2], b[4][2];
#pragma unroll
        for (int kk = 0; kk < 2; ++kk) {
            const int cfrag = kk * 4 + quad;            // data chunk 0..7
#pragma unroll
            for (int mi = 0; mi < 4; ++mi) {
                int jloc = jbase + mi * 16 + r;
                int s = cfrag ^ (r & 7);
                a[mi][kk] = *(const v8s*)(wsb + jloc * 64 + s * 8);
            }
#pragma unroll
            for (int nj = 0; nj < 4; ++nj) {
                int lloc = lbase + nj * 16 + r;
                int s = cfrag ^ (r & 7);
                b[nj][kk] = *(const v8s*)(xs + lloc * 64 + s * 8);
            }
        }
#pragma unroll
        for (int kk = 0; kk < 2; ++kk)
#pragma unroll
            for (int mi = 0; mi < 4; ++mi)
#pragma unroll
                for (int nj = 0; nj < 4; ++nj)
                    acc[mi][nj] = __builtin_amdgcn_mfma_f32_16x16x32_bf16(
                        a[mi][kk], b[nj][kk], acc[mi][nj], 0, 0, 0);
    }

    // ---- epilogue ----  j = j0 + jbase + mi*16 + quad*4 + reg, l = l0 + lbase + nj*16 + r
    const int s = jt >> 1;                 // 0=q 1=k 2=v
    unsigned short* base = (s == 0 ? q : (s == 1 ? k : v));

    float bias[4][4];
#pragma unroll
    for (int mi = 0; mi < 4; ++mi)
        *(float4*)bias[mi] = *(const float4*)(bqkv + j0 + jbase + mi * 16 + quad * 4);

    unsigned short* dstp[4];
#pragma unroll
    for (int mi = 0; mi < 4; ++mi) {
        int hh = (jt & 1) * 4 + wr * 2 + (mi >> 1);
        int d0 = (mi & 1) * 16 + quad * 4;
        dstp[mi] = base + (size_t)(n * HH + hh) * LL * DD + d0;
    }

    if (s < 2) {
#pragma unroll
        for (int nj = 0; nj < 4; ++nj) {
            float t[4][4];
            float ss[2] = {0.f, 0.f};
#pragma unroll
            for (int mi = 0; mi < 4; ++mi)
#pragma unroll
                for (int reg = 0; reg < 4; ++reg) {
                    float val = acc[mi][nj][reg] + bias[mi][reg];
                    t[mi][reg] = val;
                    ss[mi >> 1] += val * val;
                }
#pragma unroll
            for (int h2 = 0; h2 < 2; ++h2) {
                ss[h2] += __shfl_xor(ss[h2], 16);
                ss[h2] += __shfl_xor(ss[h2], 32);
                ss[h2] = rsqrtf(ss[h2]);
            }
            size_t l = (size_t)(l0 + lbase + nj * 16 + r);
#pragma unroll
            for (int mi = 0; mi < 4; ++mi) {
                float rn = ss[mi >> 1];
                v4us pk;
#pragma unroll
                for (int reg = 0; reg < 4; ++reg) pk[reg] = f2bf(t[mi][reg] * rn);
                *(v4us*)(dstp[mi] + l * DD) = pk;
            }
        }
    } else {
#pragma unroll
        for (int nj = 0; nj < 4; ++nj) {
            size_t l = (size_t)(l0 + lbase + nj * 16 + r);
#pragma unroll
            for (int mi = 0; mi < 4; ++mi) {
                v4us pk;
#pragma unroll
                for (int reg = 0; reg < 4; ++reg)
                    pk[reg] = f2bf(acc[mi][nj][reg] + bias[mi][reg]);
                *(v4us*)(dstp[mi] + l * DD) = pk;
            }
        }
    }
}

// ---------------------------------------------------------------------------
// Kernel 3: attn[n,h,d,e] = sum_l k[n,h,l,d] * v[n,h,l,e]   (bf16 in, fp32 acc)
// ---------------------------------------------------------------------------
__global__ __launch_bounds__(256) void attn_k(
    const unsigned short* __restrict__ k, const unsigned short* __restrict__ v,
    float* __restrict__ attn)
{
    __shared__ float red[4][1024];
    const int nh = blockIdx.y;
    const int wv = threadIdx.x >> 6;
    const int lane = threadIdx.x & 63;
    const int eg = lane & 7;
    const int dg = lane >> 3;
    const int l0 = blockIdx.x * 512 + wv * 128;
    const unsigned short* kb = k + (size_t)nh * LL * DD;
    const unsigned short* vb = v + (size_t)nh * LL * DD;
    float acc[4][4] = {};
#pragma unroll 4
    for (int l = l0; l < l0 + 128; ++l) {
        v4us k4 = *(const v4us*)(kb + (size_t)l * DD + dg * 4);
        v4us v4 = *(const v4us*)(vb + (size_t)l * DD + eg * 4);
        float ka[4] = {bf2f(k4[0]), bf2f(k4[1]), bf2f(k4[2]), bf2f(k4[3])};
        float va[4] = {bf2f(v4[0]), bf2f(v4[1]), bf2f(v4[2]), bf2f(v4[3])};
#pragma unroll
        for (int dp = 0; dp < 4; ++dp)
#pragma unroll
            for (int ep = 0; ep < 4; ++ep)
                acc[dp][ep] += ka[dp] * va[ep];
    }
#pragma unroll
    for (int dp = 0; dp < 4; ++dp)
#pragma unroll
        for (int ep = 0; ep < 4; ++ep)
            red[wv][(dg * 4 + dp) * 32 + eg * 4 + ep] = acc[dp][ep];
    __syncthreads();
    float* ap = attn + (size_t)nh * 1024;
    for (int i = threadIdx.x; i < 1024; i += 256)
        atomicAdd(&ap[i], red[0][i] + red[1][i] + red[2][i] + red[3][i]);
}

// ---------------------------------------------------------------------------
// Kernel 4: one block = 256 tokens of one (n,h); bf16 q/v in, bf16 mid out.
// ---------------------------------------------------------------------------
#define TOK 256
__global__ __launch_bounds__(256) void mid_k(
    const unsigned short* __restrict__ q, const unsigned short* __restrict__ v,
    const float* __restrict__ attn, const float* __restrict__ wd,
    unsigned short* __restrict__ midb)
{
    __shared__ float vt[TOK + 8][32];
    const int nh = blockIdx.y;
    const int n = nh >> 3, hh = nh & 7;
    const int l0 = blockIdx.x * TOK;
    const int tid = threadIdx.x;
    const int row = tid >> 5;
    const int e = tid & 31;
    const unsigned short* vb = v + (size_t)nh * LL * DD;

    for (int f = tid; f < (TOK + 8) * 32; f += 256) {
        int rr = f >> 5, ee = f & 31;
        int l = l0 - 4 + rr;
        vt[rr][ee] = (l >= 0 && l < LL) ? bf2f(vb[(size_t)l * DD + ee]) : 0.f;
    }

    float atc[32];
    const float* ap = attn + (size_t)nh * 1024 + e;
#pragma unroll
    for (int d = 0; d < 32; ++d) atc[d] = ap[d * 32];

    float wc[9];
#pragma unroll
    for (int r9 = 0; r9 < 9; ++r9) wc[r9] = wd[hh * 9 + r9];

    __syncthreads();

    const unsigned short* qb = q + (size_t)nh * LL * DD;
    unsigned short* ob = midb + ((size_t)n * LL) * CC + hh * DD + e;

    for (int it = 0; it < TOK / 8; ++it) {
        int lr = it * 8 + row;
        int l = l0 + lr;
        const unsigned short* qrow = qb + (size_t)l * DD;
        float s = 0.f;
#pragma unroll
        for (int d8 = 0; d8 < 4; ++d8) {
            v8u q8 = *(const v8u*)(qrow + d8 * 8);
#pragma unroll
            for (int jj = 0; jj < 8; ++jj)
                s += bf2f(q8[jj]) * atc[d8 * 8 + jj];
        }
        float t = 0.5f * vt[lr + 4][e] + 0.31830988618379067f * s;
        float ss = t * t;
#pragma unroll
        for (int off = 16; off; off >>= 1) ss += __shfl_xor(ss, off, 32);
        float o = t * rsqrtf(ss);
        float dv = 0.f;
#pragma unroll
        for (int r9 = 0; r9 < 9; ++r9) dv += wc[r9] * vt[lr + r9][e];
        ob[(size_t)l * CC] = f2bf(o + dv);
    }
}

// ---------------------------------------------------------------------------
// Kernel 5: MFMA proj GEMM (M=j, N=l), coalesced stores along l.
// ---------------------------------------------------------------------------
__global__ __launch_bounds__(256) void gemm_proj_mfma(
    const unsigned short* __restrict__ midb, const unsigned short* __restrict__ wpb,
    const float* __restrict__ bp, float* __restrict__ out)
{
    const int n  = blockIdx.z;
    const int j0 = blockIdx.x * 128;
    const int l0 = blockIdx.y * 128;
    const int tid = threadIdx.x;
    const int lane = tid & 63, wave = tid >> 6;
    const int wr = wave >> 1, wc = wave & 1;
    const int r = lane & 15, quad = lane >> 4;

    const unsigned short* abase = wpb + (size_t)(j0 + wr * 64 + r) * CC + quad * 8;
    const unsigned short* bbase = midb + (size_t)n * LL * CC
                                + (size_t)(l0 + wc * 64 + r) * CC + quad * 8;

    v4f acc[4][4];
#pragma unroll
    for (int mi = 0; mi < 4; ++mi)
#pragma unroll
        for (int nj = 0; nj < 4; ++nj) acc[mi][nj] = (v4f)(0.f);

    for (int c0 = 0; c0 < CC; c0 += 32) {
        v8s a[4], b[4];
#pragma unroll
        for (int mi = 0; mi < 4; ++mi) a[mi] = *(const v8s*)(abase + (size_t)mi * 16 * CC + c0);
#pragma unroll
        for (int nj = 0; nj < 4; ++nj) b[nj] = *(const v8s*)(bbase + (size_t)nj * 16 * CC + c0);
#pragma unroll
        for (int mi = 0; mi < 4; ++mi)
#pragma unroll
            for (int nj = 0; nj < 4; ++nj)
                acc[mi][nj] = __builtin_amdgcn_mfma_f32_16x16x32_bf16(a[mi], b[nj], acc[mi][nj], 0, 0, 0);
    }

#pragma unroll
    for (int mi = 0; mi < 4; ++mi)
#pragma unroll
        for (int reg = 0; reg < 4; ++reg) {
            int j = j0 + wr * 64 + mi * 16 + quad * 4 + reg;
            float bias = bp[j];
#pragma unroll
            for (int nj = 0; nj < 4; ++nj) {
                int l = l0 + wc * 64 + nj * 16 + r;
                out[((size_t)n * CC + j) * LL + l] = acc[mi][nj][reg] + bias;
            }
        }
}

// ---------------------------------------------------------------------------
extern "C" void kernel_launch(void* const* d_in, const int* in_sizes, int n_in,
                              void* d_out, int out_size, void* d_ws, size_t ws_size,
                              hipStream_t stream)
{
    const float* x     = (const float*)d_in[0];
    const float* wqkv  = (const float*)d_in[1];
    const float* bqkv  = (const float*)d_in[2];
    const float* wproj = (const float*)d_in[3];
    const float* bproj = (const float*)d_in[4];
    const float* wd    = (const float*)d_in[5];
    float* out = (float*)d_out;

    const size_t QKV = (size_t)NB * HH * LL * DD;       // 8388608 elems
    unsigned short* q = (unsigned short*)d_ws;
    unsigned short* k = q + QKV;
    unsigned short* v = k + QKV;
    float* attn = (float*)(v + QKV);                    // 65536 floats
    unsigned short* xb = (unsigned short*)(attn + (size_t)NB * HH * DD * DD);
    unsigned short* midb = xb;                          // disjoint live ranges
    unsigned short* wqb = xb + (size_t)NB * LL * CC;
    unsigned short* wpb = wqb + 3 * CC * CC;

    hipMemsetAsync(attn, 0, (size_t)NB * HH * DD * DD * sizeof(float), stream);

    cvt2_k<<<1024, 256, 0, stream>>>(wqkv, wproj, wqb, wpb, 3 * CC * CC, CC * CC);
    transpose_x_k<<<dim3(128, 8), 256, 0, stream>>>(x, xb);
    gemm_qkv_mfma<<<1536, 256, 0, stream>>>(xb, wqb, bqkv, q, k, v);
    attn_k<<<dim3(8, 64), 256, 0, stream>>>(k, v, attn);
    mid_k<<<dim3(LL / TOK, 64), 256, 0, stream>>>(q, v, attn, wd, midb);
    gemm_proj_mfma<<<dim3(2, 32, 8), 256, 0, stream>>>(midb, wpb, bproj, out);
}

// Round 8
// 158.276 us; speedup vs baseline: 1.4829x; 1.2861x over previous
//
#include <hip/hip_runtime.h>

#define NB 8
#define CC 256
#define HH 8
#define DD 32
#define LL 4096

typedef short v8s __attribute__((ext_vector_type(8)));
typedef float v4f __attribute__((ext_vector_type(4)));
typedef unsigned short v8u __attribute__((ext_vector_type(8)));
typedef unsigned short v4us __attribute__((ext_vector_type(4)));

__device__ __forceinline__ float4 ld4(const float* p) { return *(const float4*)p; }

// round-to-nearest-even fp32 -> bf16 (as ushort)
__device__ __forceinline__ unsigned short f2bf(float f) {
    union { float f; unsigned int u; } v; v.f = f;
    unsigned int r = (v.u + 0x7FFFu + ((v.u >> 16) & 1u)) >> 16;
    return (unsigned short)r;
}
__device__ __forceinline__ float bf2f(unsigned short u) {
    union { unsigned int u; float f; } v; v.u = ((unsigned int)u) << 16;
    return v.f;
}

// async global->LDS, 16 B per lane (dest = wave-uniform base + lane*16)
__device__ __forceinline__ void gl_lds16(const unsigned short* g, unsigned short* l) {
    __builtin_amdgcn_global_load_lds(
        (const __attribute__((address_space(1))) void*)g,
        (__attribute__((address_space(3))) void*)l, 16, 0, 0);
}

// ---------------------------------------------------------------------------
// Convert both weight matrices fp32 -> bf16 in one launch.
// ---------------------------------------------------------------------------
__global__ __launch_bounds__(256) void cvt2_k(
    const float* __restrict__ a, const float* __restrict__ b,
    unsigned short* __restrict__ da, unsigned short* __restrict__ db,
    int na, int nb)
{
    int i = blockIdx.x * 256 + threadIdx.x;
    if (i < na) da[i] = f2bf(a[i]);
    else if (i - na < nb) db[i - na] = f2bf(b[i - na]);
}

// ---------------------------------------------------------------------------
// Transpose x[N,C,L] fp32 -> xb[N,L,C] bf16.
// ---------------------------------------------------------------------------
#define PADC 264
__global__ __launch_bounds__(256) void transpose_x_k(
    const float* __restrict__ x, unsigned short* __restrict__ xb)
{
    __shared__ unsigned short t[32][PADC];
    const int n = blockIdx.y;
    const int l0 = blockIdx.x * 32;
    const float* xn = x + (size_t)n * CC * LL;
    const int lam = threadIdx.x & 31;
    const int cb = threadIdx.x >> 5;
#pragma unroll
    for (int i = 0; i < 32; ++i) {
        int c = cb * 32 + i;
        t[lam][c] = f2bf(xn[(size_t)c * LL + l0 + lam]);
    }
    __syncthreads();
    unsigned short* dst = xb + ((size_t)n * LL + l0) * CC;
    const int tid = threadIdx.x;
#pragma unroll
    for (int i = 0; i < 4; ++i) {
        int f = i * 2048 + tid * 8;
        int lr = f >> 8;
        int c2 = f & 255;
        v8u val = *(const v8u*)&t[lr][c2];
        *(v8u*)(dst + f) = val;
    }
}

// ---------------------------------------------------------------------------
// Kernel 1: MFMA qkv GEMM, m97-style LDS-staged pipeline (same as R7).
// ---------------------------------------------------------------------------
__global__ __launch_bounds__(256, 2) void gemm_qkv_mfma(
    const unsigned short* __restrict__ xb, const unsigned short* __restrict__ wqb,
    const float* __restrict__ bqkv,
    unsigned short* __restrict__ q, unsigned short* __restrict__ k,
    unsigned short* __restrict__ v)
{
    __shared__ __align__(16) unsigned short xs[8192];   // 128 rows x 64 k (swizzled)
    __shared__ __align__(16) unsigned short wsb[8192];

    const int bid  = blockIdx.x;
    const int xcd  = bid & 7;
    const int slot = bid >> 3;        // 0..191
    const int jt   = slot % 6;        // 6 j-tiles share (l,n) on one XCD
    const int p    = slot / 6;        // 0..31
    const int gp   = xcd * 32 + p;    // 0..255
    const int l0   = (gp & 31) * 128;
    const int n    = gp >> 5;
    const int j0   = jt * 128;

    const int tid = threadIdx.x;
    const int lane = tid & 63, wave = tid >> 6;
    const int wr = wave >> 1, wc = wave & 1;
    const int r = lane & 15, quad = lane >> 4;

    const int srow = wave * 8 + (lane >> 3);
    const int dchunk = (lane & 7) ^ (lane >> 3);     // global chunk for this slot
    const unsigned short* xg = xb + (size_t)n * LL * CC
                             + (size_t)(l0 + srow) * CC + dchunk * 8;
    const unsigned short* wg = wqb + (size_t)(j0 + srow) * CC + dchunk * 8;
    unsigned short* xls = xs + wave * 512 + lane * 8;
    unsigned short* wls = wsb + wave * 512 + lane * 8;

    v4f acc[4][4];
#pragma unroll
    for (int mi = 0; mi < 4; ++mi)
#pragma unroll
        for (int nj = 0; nj < 4; ++nj) acc[mi][nj] = (v4f)(0.f);

    const int jbase = wr * 64;
    const int lbase = wc * 64;

    for (int kt = 0; kt < 4; ++kt) {
        if (kt) __syncthreads();
        const int c0 = kt * 64;
#pragma unroll
        for (int i = 0; i < 4; ++i) {
            gl_lds16(xg + (size_t)i * 32 * CC + c0, xls + i * 2048);
            gl_lds16(wg + (size_t)i * 32 * CC + c0, wls + i * 2048);
        }
        __syncthreads();

        v8s a[4][2], b[4][2];
#pragma unroll
        for (int kk = 0; kk < 2; ++kk) {
            const int cfrag = kk * 4 + quad;
#pragma unroll
            for (int mi = 0; mi < 4; ++mi) {
                int jloc = jbase + mi * 16 + r;
                int s = cfrag ^ (r & 7);
                a[mi][kk] = *(const v8s*)(wsb + jloc * 64 + s * 8);
            }
#pragma unroll
            for (int nj = 0; nj < 4; ++nj) {
                int lloc = lbase + nj * 16 + r;
                int s = cfrag ^ (r & 7);
                b[nj][kk] = *(const v8s*)(xs + lloc * 64 + s * 8);
            }
        }
#pragma unroll
        for (int kk = 0; kk < 2; ++kk)
#pragma unroll
            for (int mi = 0; mi < 4; ++mi)
#pragma unroll
                for (int nj = 0; nj < 4; ++nj)
                    acc[mi][nj] = __builtin_amdgcn_mfma_f32_16x16x32_bf16(
                        a[mi][kk], b[nj][kk], acc[mi][nj], 0, 0, 0);
    }

    const int s = jt >> 1;                 // 0=q 1=k 2=v
    unsigned short* base = (s == 0 ? q : (s == 1 ? k : v));

    float bias[4][4];
#pragma unroll
    for (int mi = 0; mi < 4; ++mi)
        *(float4*)bias[mi] = *(const float4*)(bqkv + j0 + jbase + mi * 16 + quad * 4);

    unsigned short* dstp[4];
#pragma unroll
    for (int mi = 0; mi < 4; ++mi) {
        int hh = (jt & 1) * 4 + wr * 2 + (mi >> 1);
        int d0 = (mi & 1) * 16 + quad * 4;
        dstp[mi] = base + (size_t)(n * HH + hh) * LL * DD + d0;
    }

    if (s < 2) {
#pragma unroll
        for (int nj = 0; nj < 4; ++nj) {
            float t[4][4];
            float ss[2] = {0.f, 0.f};
#pragma unroll
            for (int mi = 0; mi < 4; ++mi)
#pragma unroll
                for (int reg = 0; reg < 4; ++reg) {
                    float val = acc[mi][nj][reg] + bias[mi][reg];
                    t[mi][reg] = val;
                    ss[mi >> 1] += val * val;
                }
#pragma unroll
            for (int h2 = 0; h2 < 2; ++h2) {
                ss[h2] += __shfl_xor(ss[h2], 16);
                ss[h2] += __shfl_xor(ss[h2], 32);
                ss[h2] = rsqrtf(ss[h2]);
            }
            size_t l = (size_t)(l0 + lbase + nj * 16 + r);
#pragma unroll
            for (int mi = 0; mi < 4; ++mi) {
                float rn = ss[mi >> 1];
                v4us pk;
#pragma unroll
                for (int reg = 0; reg < 4; ++reg) pk[reg] = f2bf(t[mi][reg] * rn);
                *(v4us*)(dstp[mi] + l * DD) = pk;
            }
        }
    } else {
#pragma unroll
        for (int nj = 0; nj < 4; ++nj) {
            size_t l = (size_t)(l0 + lbase + nj * 16 + r);
#pragma unroll
            for (int mi = 0; mi < 4; ++mi) {
                v4us pk;
#pragma unroll
                for (int reg = 0; reg < 4; ++reg)
                    pk[reg] = f2bf(acc[mi][nj][reg] + bias[mi][reg]);
                *(v4us*)(dstp[mi] + l * DD) = pk;
            }
        }
    }
}

// ---------------------------------------------------------------------------
// Kernel 3: attn[n,h,d,e] = sum_l k[n,h,l,d] * v[n,h,l,e]   (bf16 in, fp32 acc)
// ---------------------------------------------------------------------------
__global__ __launch_bounds__(256) void attn_k(
    const unsigned short* __restrict__ k, const unsigned short* __restrict__ v,
    float* __restrict__ attn)
{
    __shared__ float red[4][1024];
    const int nh = blockIdx.y;
    const int wv = threadIdx.x >> 6;
    const int lane = threadIdx.x & 63;
    const int eg = lane & 7;
    const int dg = lane >> 3;
    const int l0 = blockIdx.x * 512 + wv * 128;
    const unsigned short* kb = k + (size_t)nh * LL * DD;
    const unsigned short* vb = v + (size_t)nh * LL * DD;
    float acc[4][4] = {};
#pragma unroll 4
    for (int l = l0; l < l0 + 128; ++l) {
        v4us k4 = *(const v4us*)(kb + (size_t)l * DD + dg * 4);
        v4us v4 = *(const v4us*)(vb + (size_t)l * DD + eg * 4);
        float ka[4] = {bf2f(k4[0]), bf2f(k4[1]), bf2f(k4[2]), bf2f(k4[3])};
        float va[4] = {bf2f(v4[0]), bf2f(v4[1]), bf2f(v4[2]), bf2f(v4[3])};
#pragma unroll
        for (int dp = 0; dp < 4; ++dp)
#pragma unroll
            for (int ep = 0; ep < 4; ++ep)
                acc[dp][ep] += ka[dp] * va[ep];
    }
#pragma unroll
    for (int dp = 0; dp < 4; ++dp)
#pragma unroll
        for (int ep = 0; ep < 4; ++ep)
            red[wv][(dg * 4 + dp) * 32 + eg * 4 + ep] = acc[dp][ep];
    __syncthreads();
    float* ap = attn + (size_t)nh * 1024;
    for (int i = threadIdx.x; i < 1024; i += 256)
        atomicAdd(&ap[i], red[0][i] + red[1][i] + red[2][i] + red[3][i]);
}

// ---------------------------------------------------------------------------
// Kernel 4 (MFMA rewrite): one block = 256 tokens of one (n,h).
// p = q@attn via 16x16x32 MFMA (A = q frag direct from global bf16,
// B = attn column frags staged once in registers as bf16).
// C layout: row = local l (quad*4+reg), col = e (r + et*16).
// Norm over e = 4x shfl_xor{1,2,4,8}.  v tile in LDS fp32 (pad 34 = 2-way,
// free); conv taps reuse 12 staged rows per lane for 4 outputs.
// ---------------------------------------------------------------------------
#define TOK 256
__global__ __launch_bounds__(256) void mid_k(
    const unsigned short* __restrict__ q, const unsigned short* __restrict__ v,
    const float* __restrict__ attn, const float* __restrict__ wd,
    unsigned short* __restrict__ midb)
{
    __shared__ float vt[TOK + 8][34];
    const int nh = blockIdx.y;
    const int n = nh >> 3, hh = nh & 7;
    const int l0 = blockIdx.x * TOK;
    const int tid = threadIdx.x;
    const int lane = tid & 63, wave = tid >> 6;
    const int r = lane & 15, quad = lane >> 4;
    const unsigned short* vb = v + (size_t)nh * LL * DD;

    // stage v rows l0-4 .. l0+TOK+3 as fp32
    for (int f = tid; f < (TOK + 8) * 4; f += 256) {
        int row = f >> 2, seg = f & 3;
        int l = l0 - 4 + row;
        float tmp[8];
        if (l >= 0 && l < LL) {
            v8u v8 = *(const v8u*)(vb + (size_t)l * DD + seg * 8);
#pragma unroll
            for (int j = 0; j < 8; ++j) tmp[j] = bf2f(v8[j]);
        } else {
#pragma unroll
            for (int j = 0; j < 8; ++j) tmp[j] = 0.f;
        }
#pragma unroll
        for (int j = 0; j < 8; ++j) vt[row][seg * 8 + j] = tmp[j];
    }

    // attn B-frags: lane holds attn[d = quad*8+j][e = r + et*16], j = 0..7
    v8s bfrag[2];
#pragma unroll
    for (int et = 0; et < 2; ++et) {
        int e = et * 16 + r;
#pragma unroll
        for (int j = 0; j < 8; ++j)
            ((unsigned short*)&bfrag[et])[j] =
                f2bf(attn[(size_t)nh * 1024 + (quad * 8 + j) * 32 + e]);
    }

    float wc[9];
#pragma unroll
    for (int r9 = 0; r9 < 9; ++r9) wc[r9] = wd[hh * 9 + r9];

    __syncthreads();

    const unsigned short* qb = q + (size_t)nh * LL * DD;
    unsigned short* ob = midb + (size_t)n * LL * CC + hh * DD;

#pragma unroll
    for (int tp = 0; tp < 4; ++tp) {
        const int tb = wave * 64 + tp * 16;     // local token base of 16-tile
        v8s afrag = *(const v8s*)(qb + (size_t)(l0 + tb + r) * DD + quad * 8);
        v4f acc[2] = {(v4f)(0.f), (v4f)(0.f)};
#pragma unroll
        for (int et = 0; et < 2; ++et)
            acc[et] = __builtin_amdgcn_mfma_f32_16x16x32_bf16(afrag, bfrag[et], acc[et], 0, 0, 0);

        // conv source rows vt[tb + quad*4 + o][e], o = 0..11 (covers reg+r9)
        float vcol[2][12];
#pragma unroll
        for (int et = 0; et < 2; ++et) {
            int e = et * 16 + r;
#pragma unroll
            for (int o = 0; o < 12; ++o)
                vcol[et][o] = vt[tb + quad * 4 + o][e];
        }

        float t[2][4], ss[4];
#pragma unroll
        for (int reg = 0; reg < 4; ++reg) {
            t[0][reg] = 0.5f * vcol[0][4 + reg] + 0.31830988618379067f * acc[0][reg];
            t[1][reg] = 0.5f * vcol[1][4 + reg] + 0.31830988618379067f * acc[1][reg];
            ss[reg] = t[0][reg] * t[0][reg] + t[1][reg] * t[1][reg];
        }
#pragma unroll
        for (int m = 1; m < 16; m <<= 1)
#pragma unroll
            for (int reg = 0; reg < 4; ++reg)
                ss[reg] += __shfl_xor(ss[reg], m);
#pragma unroll
        for (int reg = 0; reg < 4; ++reg) ss[reg] = rsqrtf(ss[reg]);

#pragma unroll
        for (int et = 0; et < 2; ++et) {
            int e = et * 16 + r;
#pragma unroll
            for (int reg = 0; reg < 4; ++reg) {
                float dv = 0.f;
#pragma unroll
                for (int r9 = 0; r9 < 9; ++r9) dv += wc[r9] * vcol[et][reg + r9];
                int l = l0 + tb + quad * 4 + reg;
                ob[(size_t)l * CC + e] = f2bf(t[et][reg] * ss[reg] + dv);
            }
        }
    }
}

// ---------------------------------------------------------------------------
// Kernel 5: MFMA proj GEMM, m97-style LDS-staged (ported from qkv kernel).
// 2 j-tiles x 32 l x 8 n = 512 blocks; XCD swizzle pairs j-tiles per (l,n).
// ---------------------------------------------------------------------------
__global__ __launch_bounds__(256, 2) void gemm_proj_mfma(
    const unsigned short* __restrict__ midb, const unsigned short* __restrict__ wpb,
    const float* __restrict__ bp, float* __restrict__ out)
{
    __shared__ __align__(16) unsigned short xs[8192];
    __shared__ __align__(16) unsigned short wsb[8192];

    const int bid  = blockIdx.x;
    const int xcd  = bid & 7;
    const int slot = bid >> 3;        // 0..63
    const int jt   = slot & 1;
    const int p    = slot >> 1;       // 0..31
    const int gp   = xcd * 32 + p;    // 0..255
    const int l0   = (gp & 31) * 128;
    const int n    = gp >> 5;
    const int j0   = jt * 128;

    const int tid = threadIdx.x;
    const int lane = tid & 63, wave = tid >> 6;
    const int wr = wave >> 1, wc = wave & 1;
    const int r = lane & 15, quad = lane >> 4;

    const int srow = wave * 8 + (lane >> 3);
    const int dchunk = (lane & 7) ^ (lane >> 3);
    const unsigned short* xg = midb + (size_t)n * LL * CC
                             + (size_t)(l0 + srow) * CC + dchunk * 8;
    const unsigned short* wg = wpb + (size_t)(j0 + srow) * CC + dchunk * 8;
    unsigned short* xls = xs + wave * 512 + lane * 8;
    unsigned short* wls = wsb + wave * 512 + lane * 8;

    v4f acc[4][4];
#pragma unroll
    for (int mi = 0; mi < 4; ++mi)
#pragma unroll
        for (int nj = 0; nj < 4; ++nj) acc[mi][nj] = (v4f)(0.f);

    const int jbase = wr * 64;
    const int lbase = wc * 64;

    for (int kt = 0; kt < 4; ++kt) {
        if (kt) __syncthreads();
        const int c0 = kt * 64;
#pragma unroll
        for (int i = 0; i < 4; ++i) {
            gl_lds16(xg + (size_t)i * 32 * CC + c0, xls + i * 2048);
            gl_lds16(wg + (size_t)i * 32 * CC + c0, wls + i * 2048);
        }
        __syncthreads();

        v8s a[4][2], b[4][2];
#pragma unroll
        for (int kk = 0; kk < 2; ++kk) {
            const int cfrag = kk * 4 + quad;
#pragma unroll
            for (int mi = 0; mi < 4; ++mi) {
                int jloc = jbase + mi * 16 + r;
                int s = cfrag ^ (r & 7);
                a[mi][kk] = *(const v8s*)(wsb + jloc * 64 + s * 8);
            }
#pragma unroll
            for (int nj = 0; nj < 4; ++nj) {
                int lloc = lbase + nj * 16 + r;
                int s = cfrag ^ (r & 7);
                b[nj][kk] = *(const v8s*)(xs + lloc * 64 + s * 8);
            }
        }
#pragma unroll
        for (int kk = 0; kk < 2; ++kk)
#pragma unroll
            for (int mi = 0; mi < 4; ++mi)
#pragma unroll
                for (int nj = 0; nj < 4; ++nj)
                    acc[mi][nj] = __builtin_amdgcn_mfma_f32_16x16x32_bf16(
                        a[mi][kk], b[nj][kk], acc[mi][nj], 0, 0, 0);
    }

#pragma unroll
    for (int mi = 0; mi < 4; ++mi)
#pragma unroll
        for (int reg = 0; reg < 4; ++reg) {
            int j = j0 + jbase + mi * 16 + quad * 4 + reg;
            float bias = bp[j];
#pragma unroll
            for (int nj = 0; nj < 4; ++nj) {
                int l = l0 + lbase + nj * 16 + r;
                out[((size_t)n * CC + j) * LL + l] = acc[mi][nj][reg] + bias;
            }
        }
}

// ---------------------------------------------------------------------------
extern "C" void kernel_launch(void* const* d_in, const int* in_sizes, int n_in,
                              void* d_out, int out_size, void* d_ws, size_t ws_size,
                              hipStream_t stream)
{
    const float* x     = (const float*)d_in[0];
    const float* wqkv  = (const float*)d_in[1];
    const float* bqkv  = (const float*)d_in[2];
    const float* wproj = (const float*)d_in[3];
    const float* bproj = (const float*)d_in[4];
    const float* wd    = (const float*)d_in[5];
    float* out = (float*)d_out;

    const size_t QKV = (size_t)NB * HH * LL * DD;       // 8388608 elems
    unsigned short* q = (unsigned short*)d_ws;
    unsigned short* k = q + QKV;
    unsigned short* v = k + QKV;
    float* attn = (float*)(v + QKV);                    // 65536 floats
    unsigned short* xb = (unsigned short*)(attn + (size_t)NB * HH * DD * DD);
    unsigned short* midb = xb;                          // disjoint live ranges
    unsigned short* wqb = xb + (size_t)NB * LL * CC;
    unsigned short* wpb = wqb + 3 * CC * CC;

    hipMemsetAsync(attn, 0, (size_t)NB * HH * DD * DD * sizeof(float), stream);

    cvt2_k<<<1024, 256, 0, stream>>>(wqkv, wproj, wqb, wpb, 3 * CC * CC, CC * CC);
    transpose_x_k<<<dim3(128, 8), 256, 0, stream>>>(x, xb);
    gemm_qkv_mfma<<<1536, 256, 0, stream>>>(xb, wqb, bqkv, q, k, v);
    attn_k<<<dim3(8, 64), 256, 0, stream>>>(k, v, attn);
    mid_k<<<dim3(LL / TOK, 64), 256, 0, stream>>>(q, v, attn, wd, midb);
    gemm_proj_mfma<<<512, 256, 0, stream>>>(midb, wpb, bproj, out);
}

// Round 9
// 157.088 us; speedup vs baseline: 1.4941x; 1.0076x over previous
//
#include <hip/hip_runtime.h>

#define NB 8
#define CC 256
#define HH 8
#define DD 32
#define LL 4096

typedef short v8s __attribute__((ext_vector_type(8)));
typedef float v4f __attribute__((ext_vector_type(4)));
typedef unsigned short v8u __attribute__((ext_vector_type(8)));
typedef unsigned short v4us __attribute__((ext_vector_type(4)));

__device__ __forceinline__ float4 ld4(const float* p) { return *(const float4*)p; }

// round-to-nearest-even fp32 -> bf16 (as ushort)
__device__ __forceinline__ unsigned short f2bf(float f) {
    union { float f; unsigned int u; } v; v.f = f;
    unsigned int r = (v.u + 0x7FFFu + ((v.u >> 16) & 1u)) >> 16;
    return (unsigned short)r;
}
__device__ __forceinline__ float bf2f(unsigned short u) {
    union { unsigned int u; float f; } v; v.u = ((unsigned int)u) << 16;
    return v.f;
}

// async global->LDS, 16 B per lane (dest = wave-uniform base + lane*16)
__device__ __forceinline__ void gl_lds16(const unsigned short* g, unsigned short* l) {
    __builtin_amdgcn_global_load_lds(
        (const __attribute__((address_space(1))) void*)g,
        (__attribute__((address_space(3))) void*)l, 16, 0, 0);
}

// ---------------------------------------------------------------------------
// Convert both weight matrices fp32 -> bf16 AND zero the attn accumulator.
// ---------------------------------------------------------------------------
__global__ __launch_bounds__(256) void cvt2_k(
    const float* __restrict__ a, const float* __restrict__ b,
    unsigned short* __restrict__ da, unsigned short* __restrict__ db,
    float* __restrict__ attn)
{
    int i = blockIdx.x * 256 + threadIdx.x;
    if (i < 3 * CC * CC) da[i] = f2bf(a[i]);
    else if (i < 4 * CC * CC) db[i - 3 * CC * CC] = f2bf(b[i - 3 * CC * CC]);
    else attn[i - 4 * CC * CC] = 0.f;           // 65536 floats
}

// ---------------------------------------------------------------------------
// Transpose x[N,C,L] fp32 -> xb[N,L,C] bf16.
// ---------------------------------------------------------------------------
#define PADC 264
__global__ __launch_bounds__(256) void transpose_x_k(
    const float* __restrict__ x, unsigned short* __restrict__ xb)
{
    __shared__ unsigned short t[32][PADC];
    const int n = blockIdx.y;
    const int l0 = blockIdx.x * 32;
    const float* xn = x + (size_t)n * CC * LL;
    const int lam = threadIdx.x & 31;
    const int cb = threadIdx.x >> 5;
#pragma unroll
    for (int i = 0; i < 32; ++i) {
        int c = cb * 32 + i;
        t[lam][c] = f2bf(xn[(size_t)c * LL + l0 + lam]);
    }
    __syncthreads();
    unsigned short* dst = xb + ((size_t)n * LL + l0) * CC;
    const int tid = threadIdx.x;
#pragma unroll
    for (int i = 0; i < 4; ++i) {
        int f = i * 2048 + tid * 8;
        int lr = f >> 8;
        int c2 = f & 255;
        v8u val = *(const v8u*)&t[lr][c2];
        *(v8u*)(dst + f) = val;
    }
}

// ---------------------------------------------------------------------------
// Kernel 1: MFMA qkv GEMM, LDS-staged, 256j x 128l tile.
// jt in {0,1,2} selects the WHOLE q / k / v weight third (j0 = jt*256), so
// per kt there are 64 MFMA per wave between barriers (2x R7's amortization).
// LDS 48 KB -> 3 blocks/CU; grid 768 = exactly 3/CU.  XOR chunk swizzle on
// the global source keeps ds_read_b128 2-way (free).  XCD swizzle: the 3
// jt-blocks sharing an (l,n) X-tile land on one XCD.
// Fused per-head L2 norm for q/k (4 head-groups/wave, shfl 16/32).
// ---------------------------------------------------------------------------
__global__ __launch_bounds__(256, 2) void gemm_qkv_mfma(
    const unsigned short* __restrict__ xb, const unsigned short* __restrict__ wqb,
    const float* __restrict__ bqkv,
    unsigned short* __restrict__ q, unsigned short* __restrict__ k,
    unsigned short* __restrict__ v)
{
    __shared__ __align__(16) unsigned short xs[8192];    // 128 l x 64 c (swizzled)
    __shared__ __align__(16) unsigned short wsb[16384];  // 256 j x 64 c (swizzled)

    const int bid  = blockIdx.x;
    const int xcd  = bid & 7;
    const int slot = bid >> 3;        // 0..95
    const int jt   = slot % 3;        // 0=q 1=k 2=v; trio shares (l,n) X-tile
    const int p    = slot / 3;        // 0..31
    const int gp   = xcd * 32 + p;    // 0..255
    const int l0   = (gp & 31) * 128;
    const int n    = gp >> 5;
    const int j0   = jt * 256;

    const int tid = threadIdx.x;
    const int lane = tid & 63, wave = tid >> 6;
    const int wr = wave >> 1, wc = wave & 1;
    const int r = lane & 15, quad = lane >> 4;

    // staging addressing: inst covers 8 rows (lane>>3) x 8 chunk-slots (lane&7)
    const int srow = wave * 8 + (lane >> 3);
    const int dchunk = (lane & 7) ^ (lane >> 3);     // global chunk for this slot
    const unsigned short* xg = xb + (size_t)n * LL * CC
                             + (size_t)(l0 + srow) * CC + dchunk * 8;
    const unsigned short* wg = wqb + (size_t)(j0 + srow) * CC + dchunk * 8;
    unsigned short* xls = xs + wave * 512 + lane * 8;
    unsigned short* wls = wsb + wave * 512 + lane * 8;

    v4f acc[8][4];
#pragma unroll
    for (int mi = 0; mi < 8; ++mi)
#pragma unroll
        for (int nj = 0; nj < 4; ++nj) acc[mi][nj] = (v4f)(0.f);

    const int jbase = wr * 128;   // wave's j half (128 wide)
    const int lbase = wc * 64;    // wave's l half (64 wide)

    for (int kt = 0; kt < 4; ++kt) {
        if (kt) __syncthreads();
        const int c0 = kt * 64;
#pragma unroll
        for (int i = 0; i < 4; ++i)
            gl_lds16(xg + (size_t)i * 32 * CC + c0, xls + i * 2048);
#pragma unroll
        for (int i = 0; i < 8; ++i)
            gl_lds16(wg + (size_t)i * 32 * CC + c0, wls + i * 2048);
        __syncthreads();

#pragma unroll
        for (int kk = 0; kk < 2; ++kk) {
            const int cfrag = kk * 4 + quad;
            const int s = cfrag ^ (r & 7);
            v8s b[4];
#pragma unroll
            for (int nj = 0; nj < 4; ++nj) {
                int lloc = lbase + nj * 16 + r;
                b[nj] = *(const v8s*)(xs + lloc * 64 + s * 8);
            }
            v8s a[8];
#pragma unroll
            for (int mi = 0; mi < 8; ++mi) {
                int jloc = jbase + mi * 16 + r;
                a[mi] = *(const v8s*)(wsb + jloc * 64 + s * 8);
            }
#pragma unroll
            for (int mi = 0; mi < 8; ++mi)
#pragma unroll
                for (int nj = 0; nj < 4; ++nj)
                    acc[mi][nj] = __builtin_amdgcn_mfma_f32_16x16x32_bf16(
                        a[mi], b[nj], acc[mi][nj], 0, 0, 0);
        }
    }

    // ---- epilogue ----  j = j0 + jbase + mi*16 + quad*4 + reg
    unsigned short* base = (jt == 0 ? q : (jt == 1 ? k : v));

    float bias[8][4];
#pragma unroll
    for (int mi = 0; mi < 8; ++mi)
        *(float4*)bias[mi] = *(const float4*)(bqkv + j0 + jbase + mi * 16 + quad * 4);

    unsigned short* dstp[8];
#pragma unroll
    for (int mi = 0; mi < 8; ++mi) {
        int hh = wr * 4 + (mi >> 1);
        int d0 = (mi & 1) * 16 + quad * 4;
        dstp[mi] = base + (size_t)(n * HH + hh) * LL * DD + d0;
    }

    if (jt < 2) {
#pragma unroll
        for (int nj = 0; nj < 4; ++nj) {
            float t[8][4];
            float ss[4] = {0.f, 0.f, 0.f, 0.f};
#pragma unroll
            for (int mi = 0; mi < 8; ++mi)
#pragma unroll
                for (int reg = 0; reg < 4; ++reg) {
                    float val = acc[mi][nj][reg] + bias[mi][reg];
                    t[mi][reg] = val;
                    ss[mi >> 1] += val * val;
                }
#pragma unroll
            for (int h4 = 0; h4 < 4; ++h4) {
                ss[h4] += __shfl_xor(ss[h4], 16);
                ss[h4] += __shfl_xor(ss[h4], 32);
                ss[h4] = rsqrtf(ss[h4]);
            }
            size_t l = (size_t)(l0 + lbase + nj * 16 + r);
#pragma unroll
            for (int mi = 0; mi < 8; ++mi) {
                float rn = ss[mi >> 1];
                v4us pk;
#pragma unroll
                for (int reg = 0; reg < 4; ++reg) pk[reg] = f2bf(t[mi][reg] * rn);
                *(v4us*)(dstp[mi] + l * DD) = pk;
            }
        }
    } else {
#pragma unroll
        for (int nj = 0; nj < 4; ++nj) {
            size_t l = (size_t)(l0 + lbase + nj * 16 + r);
#pragma unroll
            for (int mi = 0; mi < 8; ++mi) {
                v4us pk;
#pragma unroll
                for (int reg = 0; reg < 4; ++reg)
                    pk[reg] = f2bf(acc[mi][nj][reg] + bias[mi][reg]);
                *(v4us*)(dstp[mi] + l * DD) = pk;
            }
        }
    }
}

// ---------------------------------------------------------------------------
// Kernel 3: attn[n,h,d,e] = sum_l k[n,h,l,d] * v[n,h,l,e]   (bf16 in, fp32 acc)
// ---------------------------------------------------------------------------
__global__ __launch_bounds__(256) void attn_k(
    const unsigned short* __restrict__ k, const unsigned short* __restrict__ v,
    float* __restrict__ attn)
{
    __shared__ float red[4][1024];
    const int nh = blockIdx.y;
    const int wv = threadIdx.x >> 6;
    const int lane = threadIdx.x & 63;
    const int eg = lane & 7;
    const int dg = lane >> 3;
    const int l0 = blockIdx.x * 512 + wv * 128;
    const unsigned short* kb = k + (size_t)nh * LL * DD;
    const unsigned short* vb = v + (size_t)nh * LL * DD;
    float acc[4][4] = {};
#pragma unroll 4
    for (int l = l0; l < l0 + 128; ++l) {
        v4us k4 = *(const v4us*)(kb + (size_t)l * DD + dg * 4);
        v4us v4 = *(const v4us*)(vb + (size_t)l * DD + eg * 4);
        float ka[4] = {bf2f(k4[0]), bf2f(k4[1]), bf2f(k4[2]), bf2f(k4[3])};
        float va[4] = {bf2f(v4[0]), bf2f(v4[1]), bf2f(v4[2]), bf2f(v4[3])};
#pragma unroll
        for (int dp = 0; dp < 4; ++dp)
#pragma unroll
            for (int ep = 0; ep < 4; ++ep)
                acc[dp][ep] += ka[dp] * va[ep];
    }
#pragma unroll
    for (int dp = 0; dp < 4; ++dp)
#pragma unroll
        for (int ep = 0; ep < 4; ++ep)
            red[wv][(dg * 4 + dp) * 32 + eg * 4 + ep] = acc[dp][ep];
    __syncthreads();
    float* ap = attn + (size_t)nh * 1024;
    for (int i = threadIdx.x; i < 1024; i += 256)
        atomicAdd(&ap[i], red[0][i] + red[1][i] + red[2][i] + red[3][i]);
}

// ---------------------------------------------------------------------------
// Kernel 4 (MFMA): one block = 256 tokens of one (n,h).
// ---------------------------------------------------------------------------
#define TOK 256
__global__ __launch_bounds__(256) void mid_k(
    const unsigned short* __restrict__ q, const unsigned short* __restrict__ v,
    const float* __restrict__ attn, const float* __restrict__ wd,
    unsigned short* __restrict__ midb)
{
    __shared__ float vt[TOK + 8][34];
    const int nh = blockIdx.y;
    const int n = nh >> 3, hh = nh & 7;
    const int l0 = blockIdx.x * TOK;
    const int tid = threadIdx.x;
    const int lane = tid & 63, wave = tid >> 6;
    const int r = lane & 15, quad = lane >> 4;
    const unsigned short* vb = v + (size_t)nh * LL * DD;

    for (int f = tid; f < (TOK + 8) * 4; f += 256) {
        int row = f >> 2, seg = f & 3;
        int l = l0 - 4 + row;
        float tmp[8];
        if (l >= 0 && l < LL) {
            v8u v8 = *(const v8u*)(vb + (size_t)l * DD + seg * 8);
#pragma unroll
            for (int j = 0; j < 8; ++j) tmp[j] = bf2f(v8[j]);
        } else {
#pragma unroll
            for (int j = 0; j < 8; ++j) tmp[j] = 0.f;
        }
#pragma unroll
        for (int j = 0; j < 8; ++j) vt[row][seg * 8 + j] = tmp[j];
    }

    v8s bfrag[2];
#pragma unroll
    for (int et = 0; et < 2; ++et) {
        int e = et * 16 + r;
#pragma unroll
        for (int j = 0; j < 8; ++j)
            ((unsigned short*)&bfrag[et])[j] =
                f2bf(attn[(size_t)nh * 1024 + (quad * 8 + j) * 32 + e]);
    }

    float wc[9];
#pragma unroll
    for (int r9 = 0; r9 < 9; ++r9) wc[r9] = wd[hh * 9 + r9];

    __syncthreads();

    const unsigned short* qb = q + (size_t)nh * LL * DD;
    unsigned short* ob = midb + (size_t)n * LL * CC + hh * DD;

#pragma unroll
    for (int tp = 0; tp < 4; ++tp) {
        const int tb = wave * 64 + tp * 16;
        v8s afrag = *(const v8s*)(qb + (size_t)(l0 + tb + r) * DD + quad * 8);
        v4f acc[2] = {(v4f)(0.f), (v4f)(0.f)};
#pragma unroll
        for (int et = 0; et < 2; ++et)
            acc[et] = __builtin_amdgcn_mfma_f32_16x16x32_bf16(afrag, bfrag[et], acc[et], 0, 0, 0);

        float vcol[2][12];
#pragma unroll
        for (int et = 0; et < 2; ++et) {
            int e = et * 16 + r;
#pragma unroll
            for (int o = 0; o < 12; ++o)
                vcol[et][o] = vt[tb + quad * 4 + o][e];
        }

        float t[2][4], ss[4];
#pragma unroll
        for (int reg = 0; reg < 4; ++reg) {
            t[0][reg] = 0.5f * vcol[0][4 + reg] + 0.31830988618379067f * acc[0][reg];
            t[1][reg] = 0.5f * vcol[1][4 + reg] + 0.31830988618379067f * acc[1][reg];
            ss[reg] = t[0][reg] * t[0][reg] + t[1][reg] * t[1][reg];
        }
#pragma unroll
        for (int m = 1; m < 16; m <<= 1)
#pragma unroll
            for (int reg = 0; reg < 4; ++reg)
                ss[reg] += __shfl_xor(ss[reg], m);
#pragma unroll
        for (int reg = 0; reg < 4; ++reg) ss[reg] = rsqrtf(ss[reg]);

#pragma unroll
        for (int et = 0; et < 2; ++et) {
            int e = et * 16 + r;
#pragma unroll
            for (int reg = 0; reg < 4; ++reg) {
                float dv = 0.f;
#pragma unroll
                for (int r9 = 0; r9 < 9; ++r9) dv += wc[r9] * vcol[et][reg + r9];
                int l = l0 + tb + quad * 4 + reg;
                ob[(size_t)l * CC + e] = f2bf(t[et][reg] * ss[reg] + dv);
            }
        }
    }
}

// ---------------------------------------------------------------------------
// Kernel 5: MFMA proj GEMM, m97-style LDS-staged.
// ---------------------------------------------------------------------------
__global__ __launch_bounds__(256, 2) void gemm_proj_mfma(
    const unsigned short* __restrict__ midb, const unsigned short* __restrict__ wpb,
    const float* __restrict__ bp, float* __restrict__ out)
{
    __shared__ __align__(16) unsigned short xs[8192];
    __shared__ __align__(16) unsigned short wsb[8192];

    const int bid  = blockIdx.x;
    const int xcd  = bid & 7;
    const int slot = bid >> 3;        // 0..63
    const int jt   = slot & 1;
    const int p    = slot >> 1;       // 0..31
    const int gp   = xcd * 32 + p;    // 0..255
    const int l0   = (gp & 31) * 128;
    const int n    = gp >> 5;
    const int j0   = jt * 128;

    const int tid = threadIdx.x;
    const int lane = tid & 63, wave = tid >> 6;
    const int wr = wave >> 1, wc = wave & 1;
    const int r = lane & 15, quad = lane >> 4;

    const int srow = wave * 8 + (lane >> 3);
    const int dchunk = (lane & 7) ^ (lane >> 3);
    const unsigned short* xg = midb + (size_t)n * LL * CC
                             + (size_t)(l0 + srow) * CC + dchunk * 8;
    const unsigned short* wg = wpb + (size_t)(j0 + srow) * CC + dchunk * 8;
    unsigned short* xls = xs + wave * 512 + lane * 8;
    unsigned short* wls = wsb + wave * 512 + lane * 8;

    v4f acc[4][4];
#pragma unroll
    for (int mi = 0; mi < 4; ++mi)
#pragma unroll
        for (int nj = 0; nj < 4; ++nj) acc[mi][nj] = (v4f)(0.f);

    const int jbase = wr * 64;
    const int lbase = wc * 64;

    for (int kt = 0; kt < 4; ++kt) {
        if (kt) __syncthreads();
        const int c0 = kt * 64;
#pragma unroll
        for (int i = 0; i < 4; ++i) {
            gl_lds16(xg + (size_t)i * 32 * CC + c0, xls + i * 2048);
            gl_lds16(wg + (size_t)i * 32 * CC + c0, wls + i * 2048);
        }
        __syncthreads();

        v8s a[4][2], b[4][2];
#pragma unroll
        for (int kk = 0; kk < 2; ++kk) {
            const int cfrag = kk * 4 + quad;
#pragma unroll
            for (int mi = 0; mi < 4; ++mi) {
                int jloc = jbase + mi * 16 + r;
                int s = cfrag ^ (r & 7);
                a[mi][kk] = *(const v8s*)(wsb + jloc * 64 + s * 8);
            }
#pragma unroll
            for (int nj = 0; nj < 4; ++nj) {
                int lloc = lbase + nj * 16 + r;
                int s = cfrag ^ (r & 7);
                b[nj][kk] = *(const v8s*)(xs + lloc * 64 + s * 8);
            }
        }
#pragma unroll
        for (int kk = 0; kk < 2; ++kk)
#pragma unroll
            for (int mi = 0; mi < 4; ++mi)
#pragma unroll
                for (int nj = 0; nj < 4; ++nj)
                    acc[mi][nj] = __builtin_amdgcn_mfma_f32_16x16x32_bf16(
                        a[mi][kk], b[nj][kk], acc[mi][nj], 0, 0, 0);
    }

#pragma unroll
    for (int mi = 0; mi < 4; ++mi)
#pragma unroll
        for (int reg = 0; reg < 4; ++reg) {
            int j = j0 + jbase + mi * 16 + quad * 4 + reg;
            float bias = bp[j];
#pragma unroll
            for (int nj = 0; nj < 4; ++nj) {
                int l = l0 + lbase + nj * 16 + r;
                out[((size_t)n * CC + j) * LL + l] = acc[mi][nj][reg] + bias;
            }
        }
}

// ---------------------------------------------------------------------------
extern "C" void kernel_launch(void* const* d_in, const int* in_sizes, int n_in,
                              void* d_out, int out_size, void* d_ws, size_t ws_size,
                              hipStream_t stream)
{
    const float* x     = (const float*)d_in[0];
    const float* wqkv  = (const float*)d_in[1];
    const float* bqkv  = (const float*)d_in[2];
    const float* wproj = (const float*)d_in[3];
    const float* bproj = (const float*)d_in[4];
    const float* wd    = (const float*)d_in[5];
    float* out = (float*)d_out;

    const size_t QKV = (size_t)NB * HH * LL * DD;       // 8388608 elems
    unsigned short* q = (unsigned short*)d_ws;
    unsigned short* k = q + QKV;
    unsigned short* v = k + QKV;
    float* attn = (float*)(v + QKV);                    // 65536 floats
    unsigned short* xb = (unsigned short*)(attn + (size_t)NB * HH * DD * DD);
    unsigned short* midb = xb;                          // disjoint live ranges
    unsigned short* wqb = xb + (size_t)NB * LL * CC;
    unsigned short* wpb = wqb + 3 * CC * CC;

    // cvt (4*CC*CC elems) + attn zero (65536) = 327680 threads = 1280 blocks
    cvt2_k<<<1280, 256, 0, stream>>>(wqkv, wproj, wqb, wpb, attn);
    transpose_x_k<<<dim3(128, 8), 256, 0, stream>>>(x, xb);
    gemm_qkv_mfma<<<768, 256, 0, stream>>>(xb, wqb, bqkv, q, k, v);
    attn_k<<<dim3(8, 64), 256, 0, stream>>>(k, v, attn);
    mid_k<<<dim3(LL / TOK, 64), 256, 0, stream>>>(q, v, attn, wd, midb);
    gemm_proj_mfma<<<512, 256, 0, stream>>>(midb, wpb, bproj, out);
}